// Round 1
// baseline (1052.905 us; speedup 1.0000x reference)
//
#include <hip/hip_runtime.h>

#define TT 4
#define BB 32
#define CC 512
#define NN 256
#define DH 64

typedef unsigned char u8;
typedef unsigned long long u64;

// ---- helpers ----------------------------------------------------------
static __device__ __forceinline__ unsigned int pack4(unsigned int w){
  // bytes (0/1) of w -> 4 bits, bit i = byte i
  return (w & 1u) | ((w >> 7) & 2u) | ((w >> 14) & 4u) | ((w >> 21) & 8u);
}

// ---- K1: LIF on x -> binary spikes ------------------------------------
__global__ __launch_bounds__(256) void k_lif_x(const float* __restrict__ x,
                                               u8* __restrict__ xs){
  const int PL = BB*CC*NN;
  int i = blockIdx.x*256 + threadIdx.x;
  float v = 0.f;
#pragma unroll
  for (int t=0;t<TT;++t){
    float xv = x[(size_t)t*PL + i];
    v = v + (xv - v)*0.5f;           // v' = v + (x - v)/tau, tau = 2
    if (v >= 1.0f){ xs[(size_t)t*PL + i] = 1; v = 0.f; }
    else          { xs[(size_t)t*PL + i] = 0; }
  }
}

// ---- K2/K4: y = W @ spikes  (+bias) -> BN -> LIF over T -> spikes -----
// block: 64(d) x 64(n) tile for one b, all T=4 timesteps.
// accumulation strictly sequential over c ascending (matches np einsum).
__global__ __launch_bounds__(256) void k_gemm_bn_lif(
    const u8* __restrict__ act, const float* __restrict__ w,
    const float* __restrict__ bias,
    const float* __restrict__ bg, const float* __restrict__ bb,
    const float* __restrict__ bm, const float* __restrict__ bv,
    u8* __restrict__ out, float vth)
{
  __shared__ float Wt[32][68];       // [c_local][d_local] (transposed)
  __shared__ float Xt[TT][32][68];   // [t][c_local][n_local]

  const int b  = blockIdx.y;
  const int d0 = (blockIdx.x >> 2) * 64;
  const int n0 = (blockIdx.x & 3) * 64;
  const int tid = threadIdx.x;
  const int td = tid >> 4, tn = tid & 15;

  float acc[TT][4][4] = {};

  for (int c0 = 0; c0 < CC; c0 += 32){
    { // stage W chunk (transposed for contiguous d-reads)
      int dl = tid >> 2;
      int cb = (tid & 3) * 8;
      const float* wp = w + (size_t)(d0+dl)*CC + c0 + cb;
      float4 w0 = *(const float4*)wp;
      float4 w1 = *(const float4*)(wp+4);
      Wt[cb+0][dl]=w0.x; Wt[cb+1][dl]=w0.y; Wt[cb+2][dl]=w0.z; Wt[cb+3][dl]=w0.w;
      Wt[cb+4][dl]=w1.x; Wt[cb+5][dl]=w1.y; Wt[cb+6][dl]=w1.z; Wt[cb+7][dl]=w1.w;
    }
    { // stage spike chunk for all 4 timesteps, u8 -> f32
      int cl = tid >> 3;
      int nb = (tid & 7) * 8;
#pragma unroll
      for (int t=0;t<TT;++t){
        const u8* ap = act + ((size_t)t*BB + b)*CC*NN + (size_t)(c0+cl)*NN + n0 + nb;
        uint2 u = *(const uint2*)ap;
#pragma unroll
        for (int q=0;q<4;++q) Xt[t][cl][nb+q]   = (float)((u.x >> (8*q)) & 0xffu);
#pragma unroll
        for (int q=0;q<4;++q) Xt[t][cl][nb+4+q] = (float)((u.y >> (8*q)) & 0xffu);
      }
    }
    __syncthreads();
#pragma unroll 4
    for (int kk=0;kk<32;++kk){
      float4 a4 = *(const float4*)&Wt[kk][td*4];
      float av[4] = {a4.x, a4.y, a4.z, a4.w};
#pragma unroll
      for (int t=0;t<TT;++t){
        float4 x4 = *(const float4*)&Xt[t][kk][tn*4];
        float xv[4] = {x4.x, x4.y, x4.z, x4.w};
#pragma unroll
        for (int i=0;i<4;++i)
#pragma unroll
          for (int j=0;j<4;++j)
            acc[t][i][j] = fmaf(av[i], xv[j], acc[t][i][j]);
      }
    }
    __syncthreads();
  }

  // epilogue: (+bias) -> BN -> LIF(T) -> u8 spikes
#pragma unroll
  for (int i=0;i<4;++i){
    int d = d0 + td*4 + i;
    float inv = bg[d] / sqrtf(bv[d] + 1e-5f);
    float mu = bm[d], be = bb[d];
    float bs = bias ? bias[d] : 0.0f;
    u8 sp[TT][4];
#pragma unroll
    for (int j=0;j<4;++j){
      float vm = 0.f;
#pragma unroll
      for (int t=0;t<TT;++t){
        float y  = acc[t][i][j] + bs;
        float yb = (y - mu)*inv + be;
        vm = vm + (yb - vm)*0.5f;
        if (vm >= vth){ sp[t][j] = 1; vm = 0.f; } else sp[t][j] = 0;
      }
    }
#pragma unroll
    for (int t=0;t<TT;++t){
      uchar4 s4 = make_uchar4(sp[t][0], sp[t][1], sp[t][2], sp[t][3]);
      *(uchar4*)(out + ((size_t)t*BB + b)*CC*NN + (size_t)d*NN + n0 + tn*4) = s4;
    }
  }
}

// ---- K3: attention per (b,h): kv = k^T v (popcount, exact),
//          o = q@kv * 0.125 (exact ints), LIF(0.5) over T -------------
__global__ __launch_bounds__(256) void k_attn(const u8* __restrict__ qs,
                                              const u8* __restrict__ ks,
                                              const u8* __restrict__ vs,
                                              u8* __restrict__ os)
{
  const int h = blockIdx.x, b = blockIdx.y;
  __shared__ u64 Kb[64][4];
  __shared__ u64 Vb[64][4];
  __shared__ float kvf[64][64];
  const int tid = threadIdx.x;

  float4 vm[16];
#pragma unroll
  for (int e=0;e<16;++e) vm[e] = make_float4(0.f,0.f,0.f,0.f);

  for (int t=0;t<TT;++t){
    size_t base = ((size_t)t*BB + b)*CC*NN + (size_t)h*DH*NN;
    // bitpack K,V planes: Kb[d] = 256 bits over n
#pragma unroll
    for (int p=0;p<4;++p){
      int idx = p*256 + tid;
      int d = idx >> 4;
      int piece = idx & 15;
      uint4 ku = *(const uint4*)(ks + base + (size_t)d*NN + piece*16);
      uint4 vu = *(const uint4*)(vs + base + (size_t)d*NN + piece*16);
      unsigned int kp16 = pack4(ku.x) | (pack4(ku.y)<<4) | (pack4(ku.z)<<8) | (pack4(ku.w)<<12);
      unsigned int vp16 = pack4(vu.x) | (pack4(vu.y)<<4) | (pack4(vu.z)<<8) | (pack4(vu.w)<<12);
      ((unsigned short*)Kb)[d*16 + piece] = (unsigned short)kp16;
      ((unsigned short*)Vb)[d*16 + piece] = (unsigned short)vp16;
    }
    __syncthreads();
    { // kv[d][e] = popcount(K[d] & V[e])  (exact integer)
      int dd0 = (tid >> 4)*4, ee0 = (tid & 15)*4;
      int cnt[4][4] = {};
#pragma unroll
      for (int wi=0; wi<4; ++wi){
        u64 kw[4], vw[4];
#pragma unroll
        for (int i=0;i<4;++i) kw[i] = Kb[dd0+i][wi];
#pragma unroll
        for (int j=0;j<4;++j) vw[j] = Vb[ee0+j][wi];
#pragma unroll
        for (int i=0;i<4;++i)
#pragma unroll
          for (int j=0;j<4;++j)
            cnt[i][j] += __popcll(kw[i] & vw[j]);
      }
#pragma unroll
      for (int i=0;i<4;++i)
#pragma unroll
        for (int j=0;j<4;++j)
          kvf[dd0+i][ee0+j] = (float)cnt[i][j];
    }
    __syncthreads();
    // o[n=tid][e] = sum_d q[d][n] * kv[d][e]; then *0.125, LIF(0.5)
    float4 acc[16];
#pragma unroll
    for (int e=0;e<16;++e) acc[e] = make_float4(0.f,0.f,0.f,0.f);
    const u8* qb = qs + base + tid;
    for (int d=0; d<64; ++d){
      float qf = (float)qb[(size_t)d*NN];
      const float4* kr = (const float4*)&kvf[d][0];
#pragma unroll
      for (int e=0;e<16;++e){
        float4 k4 = kr[e];
        acc[e].x = fmaf(qf, k4.x, acc[e].x);
        acc[e].y = fmaf(qf, k4.y, acc[e].y);
        acc[e].z = fmaf(qf, k4.z, acc[e].z);
        acc[e].w = fmaf(qf, k4.w, acc[e].w);
      }
    }
    u8* ob = os + base + tid;
#pragma unroll
    for (int e=0;e<16;++e){
      float o; u8 s;
      o = acc[e].x*0.125f; vm[e].x += (o - vm[e].x)*0.5f; s = (vm[e].x >= 0.5f); ob[(size_t)(e*4+0)*NN] = s; if (s) vm[e].x = 0.f;
      o = acc[e].y*0.125f; vm[e].y += (o - vm[e].y)*0.5f; s = (vm[e].y >= 0.5f); ob[(size_t)(e*4+1)*NN] = s; if (s) vm[e].y = 0.f;
      o = acc[e].z*0.125f; vm[e].z += (o - vm[e].z)*0.5f; s = (vm[e].z >= 0.5f); ob[(size_t)(e*4+2)*NN] = s; if (s) vm[e].z = 0.f;
      o = acc[e].w*0.125f; vm[e].w += (o - vm[e].w)*0.5f; s = (vm[e].w >= 0.5f); ob[(size_t)(e*4+3)*NN] = s; if (s) vm[e].w = 0.f;
    }
    // next-iter pack touches Kb/Vb only; pack->sync already orders vs kvf reads
  }
}

// ---- K5: depthwise 5x5 + bias -> BN -> + identity ---------------------
__global__ __launch_bounds__(256) void k_dwc(const u8* __restrict__ zs,
                                             const float* __restrict__ x,
                                             const float* __restrict__ dwc_w,
                                             const float* __restrict__ dwc_b,
                                             const float* __restrict__ g4,
                                             const float* __restrict__ b4,
                                             const float* __restrict__ m4,
                                             const float* __restrict__ v4,
                                             float* __restrict__ out)
{
  const int c = blockIdx.x, b = blockIdx.y, t = blockIdx.z;
  __shared__ float zp[20][20];
  __shared__ float wk[25];
  const int tid = threadIdx.x;
  size_t base = (((size_t)t*BB + b)*CC + c)*NN;

  for (int idx = tid; idx < 400; idx += 256){
    int yy = idx/20 - 2, xx = idx%20 - 2;
    float v = 0.f;
    if (yy >= 0 && yy < 16 && xx >= 0 && xx < 16) v = (float)zs[base + yy*16 + xx];
    zp[idx/20][idx%20] = v;
  }
  if (tid < 25) wk[tid] = dwc_w[c*25 + tid];
  __syncthreads();

  const int py = tid >> 4, px = tid & 15;
  float s = 0.f;
#pragma unroll
  for (int i=0;i<5;++i)
#pragma unroll
    for (int j=0;j<5;++j)
      s = fmaf(zp[py+i][px+j], wk[i*5+j], s);
  s += dwc_b[c];
  float inv = g4[c] / sqrtf(v4[c] + 1e-5f);
  float r = (s - m4[c])*inv + b4[c] + x[base + tid];
  out[base + tid] = r;
}

// ---- launch -----------------------------------------------------------
extern "C" void kernel_launch(void* const* d_in, const int* in_sizes, int n_in,
                              void* d_out, int out_size, void* d_ws, size_t ws_size,
                              hipStream_t stream) {
  const float* x      = (const float*)d_in[0];
  const float* q_w    = (const float*)d_in[1];
  const float* k_w    = (const float*)d_in[2];
  const float* v_w    = (const float*)d_in[3];
  const float* proj_w = (const float*)d_in[4];
  const float* proj_b = (const float*)d_in[5];
  const float* dwc_w  = (const float*)d_in[6];
  const float* dwc_b  = (const float*)d_in[7];
  const float* bn_g   = (const float*)d_in[8];
  const float* bn_b   = (const float*)d_in[9];
  const float* bn_m   = (const float*)d_in[10];
  const float* bn_v   = (const float*)d_in[11];
  float* out = (float*)d_out;

  const size_t SZ = (size_t)TT*BB*CC*NN;   // 16,777,216
  u8* xs = (u8*)d_ws;
  u8* qs = xs + SZ;
  u8* ks = qs + SZ;
  u8* vs = ks + SZ;
  u8* os = vs + SZ;
  u8* zsp = os + SZ;

  // 1) input LIF
  k_lif_x<<<(BB*CC*NN)/256, 256, 0, stream>>>(x, xs);

  // 2) q,k,v: matmul + BN(0/1/2) + LIF(1.0)
  dim3 gg(32, BB);
  k_gemm_bn_lif<<<gg, 256, 0, stream>>>(xs, q_w, nullptr,
      bn_g + 0*CC, bn_b + 0*CC, bn_m + 0*CC, bn_v + 0*CC, qs, 1.0f);
  k_gemm_bn_lif<<<gg, 256, 0, stream>>>(xs, k_w, nullptr,
      bn_g + 1*CC, bn_b + 1*CC, bn_m + 1*CC, bn_v + 1*CC, ks, 1.0f);
  k_gemm_bn_lif<<<gg, 256, 0, stream>>>(xs, v_w, nullptr,
      bn_g + 2*CC, bn_b + 2*CC, bn_m + 2*CC, bn_v + 2*CC, vs, 1.0f);

  // 3) attention (exact) + LIF(0.5)
  k_attn<<<dim3(8, BB), 256, 0, stream>>>(qs, ks, vs, os);

  // 4) proj: matmul + bias + BN(3) + LIF(1.0)
  k_gemm_bn_lif<<<gg, 256, 0, stream>>>(os, proj_w, proj_b,
      bn_g + 3*CC, bn_b + 3*CC, bn_m + 3*CC, bn_v + 3*CC, zsp, 1.0f);

  // 5) depthwise conv + BN(4) + residual
  k_dwc<<<dim3(CC, BB, TT), 256, 0, stream>>>(zsp, x, dwc_w, dwc_b,
      bn_g + 4*CC, bn_b + 4*CC, bn_m + 4*CC, bn_v + 4*CC, out);
}

// Round 2
// 443.154 us; speedup vs baseline: 2.3759x; 2.3759x over previous
//
#include <hip/hip_runtime.h>

#define TT 4
#define BB 32
#define CC 512
#define NN 256
#define DH 64

typedef unsigned char u8;
typedef unsigned short ushort_t;
typedef unsigned int uint_t;
typedef unsigned long long u64;

typedef short bf16x8 __attribute__((ext_vector_type(8)));
typedef float f32x4 __attribute__((ext_vector_type(4)));

// ---- helpers ----------------------------------------------------------
static __device__ __forceinline__ unsigned int pack4(unsigned int w){
  return (w & 1u) | ((w >> 7) & 2u) | ((w >> 14) & 4u) | ((w >> 21) & 8u);
}
static __device__ __forceinline__ unsigned int f2bf(float f){
  unsigned int u = __float_as_uint(f);
  return (u + 0x7FFFu + ((u >> 16) & 1u)) >> 16;   // RNE
}
static __device__ __forceinline__ float bf2f(unsigned int b){
  return __uint_as_float(b << 16);
}

// ---- K0: prep — weight 3-way bf16 split + folded BN params ------------
__global__ __launch_bounds__(256) void k_prep(
    const float* __restrict__ qw, const float* __restrict__ kw,
    const float* __restrict__ vw, const float* __restrict__ pw,
    const float* __restrict__ bg, const float* __restrict__ bb,
    const float* __restrict__ bm, const float* __restrict__ bv,
    const float* __restrict__ pb,
    ushort_t* __restrict__ wsp, float* __restrict__ bn2)
{
  int bid = blockIdx.x;
  if (bid < 4096){
    int idx = bid*256 + threadIdx.x;      // 4 * 512*512
    int g   = idx >> 18;
    int rem = idx & 262143;
    const float* W = (g==0)? qw : (g==1)? kw : (g==2)? vw : pw;
    float wv = W[rem];
    unsigned int u1 = f2bf(wv);  float r1 = wv - bf2f(u1);
    unsigned int u2 = f2bf(r1);  float r2 = r1 - bf2f(u2);
    unsigned int u3 = f2bf(r2);
    size_t base = (size_t)g*3*262144 + rem;
    wsp[base            ] = (ushort_t)u1;
    wsp[base + 262144   ] = (ushort_t)u2;
    wsp[base + 2*262144 ] = (ushort_t)u3;
  } else {
    for (int i = threadIdx.x; i < 2048; i += 256){
      int g = i >> 9, d = i & 511;
      float inv = bg[g*512+d] / sqrtf(bv[g*512+d] + 1e-5f);
      float bt  = bb[g*512+d] - bm[g*512+d]*inv + ((g==3)? pb[d]*inv : 0.f);
      bn2[i*2+0] = inv;
      bn2[i*2+1] = bt;
    }
  }
}

// ---- K1: LIF on x -> binary spikes ------------------------------------
__global__ __launch_bounds__(256) void k_lif_x(const float* __restrict__ x,
                                               u8* __restrict__ xs){
  const int PL = BB*CC*NN;
  int i = blockIdx.x*256 + threadIdx.x;
  float v = 0.f;
#pragma unroll
  for (int t=0;t<TT;++t){
    float xv = x[(size_t)t*PL + i];
    v = v + (xv - v)*0.5f;
    if (v >= 1.0f){ xs[(size_t)t*PL + i] = 1; v = 0.f; }
    else          { xs[(size_t)t*PL + i] = 0; }
  }
}

// ---- K2: MFMA GEMM (3-split bf16) + BN + LIF --------------------------
// block: 128d x 64n x 4t for one b.  4 waves, each 32d x 64n x 4t.
__global__ __launch_bounds__(256, 2) void k_gemm_mfma(
    const u8* __restrict__ act, const ushort_t* __restrict__ wsp,
    const float* __restrict__ bn2, u8* __restrict__ out, float vth)
{
  __shared__ __align__(16) ushort_t Alds[3][128][32];   // [split][d][k]
  __shared__ __align__(16) ushort_t Blds[4][4][17][32]; // [t][nf][n%16(+pad)][k]

  const int b  = blockIdx.y;
  const int d0 = (blockIdx.x >> 2) * 128;
  const int n0 = (blockIdx.x & 3) * 64;
  const int tid = threadIdx.x;
  const int l   = tid & 63;
  const int wvi = tid >> 6;

  f32x4 acc[2][4][4];
#pragma unroll
  for (int df=0; df<2; ++df)
#pragma unroll
    for (int nf=0; nf<4; ++nf)
#pragma unroll
      for (int t=0; t<4; ++t)
        acc[df][nf][t] = (f32x4){0.f,0.f,0.f,0.f};

  // B-stage thread mapping
  const int ts = tid >> 6;
  const int kp = (tid >> 2) & 15;
  const int nr = tid & 3;
  const int kq = kp >> 2, jj = kp & 3;

  for (int c0 = 0; c0 < CC; c0 += 32){
    // ---- stage A: 3 splits x 128d x 32c bf16 (6 x 16B per thread) ----
#pragma unroll
    for (int q=0; q<6; ++q){
      int id = q*256 + tid;               // 0..1535
      int s  = id / 512;
      int rm = id & 511;
      int d  = rm >> 2, cc4 = rm & 3;
      const ushort_t* gp = wsp + ((size_t)s*512 + 0)*512   // split-major
                         + (size_t)(0) ;                   // (placeholder, real below)
      gp = wsp + (size_t)s*262144 + (size_t)(d0 + d)*512 + c0 + cc4*8;
      *(uint4*)&Alds[s][d][cc4*8] = *(const uint4*)gp;
    }
    // ---- stage B: spikes u8 -> bf16, 2 c-rows x 16 n per thread ----
    {
      const u8* sp = act + (((size_t)ts*BB + b)*CC + (c0 + kp*2))*NN + n0 + nr*16;
      uint4 r0 = *(const uint4*)sp;
      uint4 r1 = *(const uint4*)(sp + NN);
      uint_t wa[4] = {r0.x, r0.y, r0.z, r0.w};
      uint_t wb[4] = {r1.x, r1.y, r1.z, r1.w};
#pragma unroll
      for (int c4=0; c4<4; ++c4){
#pragma unroll
        for (int by=0; by<4; ++by){
          int i = c4*4 + by;
          uint_t b0 = (wa[c4] >> (8*by)) & 1u;
          uint_t b1 = (wb[c4] >> (8*by)) & 1u;
          uint_t hv = b0*0x3F80u + b1*0x3F800000u;  // two bf16 (c, c+1)
          *((uint_t*)&Blds[ts][nr][i][kq*8] + jj) = hv;
        }
      }
    }
    __syncthreads();

    // ---- fragments + MFMA ----
    bf16x8 Af[3][2];
#pragma unroll
    for (int s=0; s<3; ++s)
#pragma unroll
      for (int df=0; df<2; ++df)
        Af[s][df] = *(const bf16x8*)&Alds[s][wvi*32 + df*16 + (l&15)][(l>>4)*8];

#pragma unroll
    for (int nf=0; nf<4; ++nf){
      bf16x8 Bf[4];
#pragma unroll
      for (int t=0; t<4; ++t)
        Bf[t] = *(const bf16x8*)&Blds[t][nf][l&15][(l>>4)*8];
#pragma unroll
      for (int s=0; s<3; ++s)
#pragma unroll
        for (int df=0; df<2; ++df)
#pragma unroll
          for (int t=0; t<4; ++t)
            acc[df][nf][t] = __builtin_amdgcn_mfma_f32_16x16x32_bf16(
                Af[s][df], Bf[t], acc[df][nf][t], 0, 0, 0);
    }
    __syncthreads();
  }

  // ---- epilogue: BN -> LIF(T) -> u8 spikes ----
#pragma unroll
  for (int df=0; df<2; ++df){
#pragma unroll
    for (int r=0; r<4; ++r){
      int d = d0 + wvi*32 + df*16 + ((l>>4)<<2) + r;
      float inv = bn2[d*2+0], bt = bn2[d*2+1];
#pragma unroll
      for (int nf=0; nf<4; ++nf){
        int n = n0 + nf*16 + (l&15);
        float v = 0.f;
#pragma unroll
        for (int t=0; t<4; ++t){
          float y = acc[df][nf][t][r] * inv + bt;
          v = v + (y - v)*0.5f;
          u8 s = (v >= vth);
          out[(((size_t)t*BB + b)*CC + d)*NN + n] = s;
          if (s) v = 0.f;
        }
      }
    }
  }
}

// ---- K3: attention per (b,h) ------------------------------------------
__global__ __launch_bounds__(256) void k_attn(const u8* __restrict__ qs,
                                              const u8* __restrict__ ks,
                                              const u8* __restrict__ vs,
                                              u8* __restrict__ os)
{
  const int h = blockIdx.x, b = blockIdx.y;
  __shared__ u64 Kb[64][4];
  __shared__ u64 Vb[64][4];
  __shared__ float kvf[64][64];
  const int tid = threadIdx.x;

  float4 vm[16];
#pragma unroll
  for (int e=0;e<16;++e) vm[e] = make_float4(0.f,0.f,0.f,0.f);

  for (int t=0;t<TT;++t){
    size_t base = ((size_t)t*BB + b)*CC*NN + (size_t)h*DH*NN;
#pragma unroll
    for (int p=0;p<4;++p){
      int idx = p*256 + tid;
      int d = idx >> 4;
      int piece = idx & 15;
      uint4 ku = *(const uint4*)(ks + base + (size_t)d*NN + piece*16);
      uint4 vu = *(const uint4*)(vs + base + (size_t)d*NN + piece*16);
      unsigned int kp16 = pack4(ku.x) | (pack4(ku.y)<<4) | (pack4(ku.z)<<8) | (pack4(ku.w)<<12);
      unsigned int vp16 = pack4(vu.x) | (pack4(vu.y)<<4) | (pack4(vu.z)<<8) | (pack4(vu.w)<<12);
      ((unsigned short*)Kb)[d*16 + piece] = (unsigned short)kp16;
      ((unsigned short*)Vb)[d*16 + piece] = (unsigned short)vp16;
    }
    __syncthreads();
    {
      int dd0 = (tid >> 4)*4, ee0 = (tid & 15)*4;
      int cnt[4][4] = {};
#pragma unroll
      for (int wi=0; wi<4; ++wi){
        u64 kw[4], vw[4];
#pragma unroll
        for (int i=0;i<4;++i) kw[i] = Kb[dd0+i][wi];
#pragma unroll
        for (int j=0;j<4;++j) vw[j] = Vb[ee0+j][wi];
#pragma unroll
        for (int i=0;i<4;++i)
#pragma unroll
          for (int j=0;j<4;++j)
            cnt[i][j] += __popcll(kw[i] & vw[j]);
      }
#pragma unroll
      for (int i=0;i<4;++i)
#pragma unroll
        for (int j=0;j<4;++j)
          kvf[dd0+i][ee0+j] = (float)cnt[i][j];
    }
    __syncthreads();
    float4 acc[16];
#pragma unroll
    for (int e=0;e<16;++e) acc[e] = make_float4(0.f,0.f,0.f,0.f);
    const u8* qb = qs + base + tid;
    for (int d=0; d<64; ++d){
      float qf = (float)qb[(size_t)d*NN];
      const float4* kr = (const float4*)&kvf[d][0];
#pragma unroll
      for (int e=0;e<16;++e){
        float4 k4 = kr[e];
        acc[e].x = fmaf(qf, k4.x, acc[e].x);
        acc[e].y = fmaf(qf, k4.y, acc[e].y);
        acc[e].z = fmaf(qf, k4.z, acc[e].z);
        acc[e].w = fmaf(qf, k4.w, acc[e].w);
      }
    }
    u8* ob = os + base + tid;
#pragma unroll
    for (int e=0;e<16;++e){
      float o; u8 s;
      o = acc[e].x*0.125f; vm[e].x += (o - vm[e].x)*0.5f; s = (vm[e].x >= 0.5f); ob[(size_t)(e*4+0)*NN] = s; if (s) vm[e].x = 0.f;
      o = acc[e].y*0.125f; vm[e].y += (o - vm[e].y)*0.5f; s = (vm[e].y >= 0.5f); ob[(size_t)(e*4+1)*NN] = s; if (s) vm[e].y = 0.f;
      o = acc[e].z*0.125f; vm[e].z += (o - vm[e].z)*0.5f; s = (vm[e].z >= 0.5f); ob[(size_t)(e*4+2)*NN] = s; if (s) vm[e].z = 0.f;
      o = acc[e].w*0.125f; vm[e].w += (o - vm[e].w)*0.5f; s = (vm[e].w >= 0.5f); ob[(size_t)(e*4+3)*NN] = s; if (s) vm[e].w = 0.f;
    }
  }
}

// ---- K5: depthwise 5x5 + bias -> BN -> + identity ---------------------
__global__ __launch_bounds__(256) void k_dwc(const u8* __restrict__ zs,
                                             const float* __restrict__ x,
                                             const float* __restrict__ dwc_w,
                                             const float* __restrict__ dwc_b,
                                             const float* __restrict__ g4,
                                             const float* __restrict__ b4,
                                             const float* __restrict__ m4,
                                             const float* __restrict__ v4,
                                             float* __restrict__ out)
{
  const int c = blockIdx.x, b = blockIdx.y, t = blockIdx.z;
  __shared__ float zp[20][20];
  __shared__ float wk[25];
  const int tid = threadIdx.x;
  size_t base = (((size_t)t*BB + b)*CC + c)*NN;

  for (int idx = tid; idx < 400; idx += 256){
    int yy = idx/20 - 2, xx = idx%20 - 2;
    float v = 0.f;
    if (yy >= 0 && yy < 16 && xx >= 0 && xx < 16) v = (float)zs[base + yy*16 + xx];
    zp[idx/20][idx%20] = v;
  }
  if (tid < 25) wk[tid] = dwc_w[c*25 + tid];
  __syncthreads();

  const int py = tid >> 4, px = tid & 15;
  float s = 0.f;
#pragma unroll
  for (int i=0;i<5;++i)
#pragma unroll
    for (int j=0;j<5;++j)
      s = fmaf(zp[py+i][px+j], wk[i*5+j], s);
  s += dwc_b[c];
  float inv = g4[c] / sqrtf(v4[c] + 1e-5f);
  float r = (s - m4[c])*inv + b4[c] + x[base + tid];
  out[base + tid] = r;
}

// ---- launch -----------------------------------------------------------
extern "C" void kernel_launch(void* const* d_in, const int* in_sizes, int n_in,
                              void* d_out, int out_size, void* d_ws, size_t ws_size,
                              hipStream_t stream) {
  const float* x      = (const float*)d_in[0];
  const float* q_w    = (const float*)d_in[1];
  const float* k_w    = (const float*)d_in[2];
  const float* v_w    = (const float*)d_in[3];
  const float* proj_w = (const float*)d_in[4];
  const float* proj_b = (const float*)d_in[5];
  const float* dwc_w  = (const float*)d_in[6];
  const float* dwc_b  = (const float*)d_in[7];
  const float* bn_g   = (const float*)d_in[8];
  const float* bn_b   = (const float*)d_in[9];
  const float* bn_m   = (const float*)d_in[10];
  const float* bn_v   = (const float*)d_in[11];
  float* out = (float*)d_out;

  const size_t SZ = (size_t)TT*BB*CC*NN;   // 16,777,216
  u8* xs  = (u8*)d_ws;
  u8* qs  = xs + SZ;
  u8* ks  = qs + SZ;
  u8* vs  = ks + SZ;
  u8* os  = vs + SZ;
  u8* zsp = os + SZ;
  ushort_t* wsp = (ushort_t*)(zsp + SZ);          // 4*3*512*512 bf16 = 6.29MB
  float* bn2    = (float*)(wsp + (size_t)4*3*262144);  // 4*512*2 f32

  // 0) prep: weight splits + BN folds
  k_prep<<<4097, 256, 0, stream>>>(q_w, k_w, v_w, proj_w,
      bn_g, bn_b, bn_m, bn_v, proj_b, wsp, bn2);

  // 1) input LIF
  k_lif_x<<<(BB*CC*NN)/256, 256, 0, stream>>>(x, xs);

  // 2) q,k,v: MFMA matmul + BN(0/1/2) + LIF(1.0)
  dim3 gg(16, BB);
  k_gemm_mfma<<<gg, 256, 0, stream>>>(xs, wsp + (size_t)0*3*262144, bn2 + 0*1024, qs, 1.0f);
  k_gemm_mfma<<<gg, 256, 0, stream>>>(xs, wsp + (size_t)1*3*262144, bn2 + 1*1024, ks, 1.0f);
  k_gemm_mfma<<<gg, 256, 0, stream>>>(xs, wsp + (size_t)2*3*262144, bn2 + 2*1024, vs, 1.0f);

  // 3) attention (exact) + LIF(0.5)
  k_attn<<<dim3(8, BB), 256, 0, stream>>>(qs, ks, vs, os);

  // 4) proj: MFMA matmul + bias + BN(3) + LIF(1.0)
  k_gemm_mfma<<<gg, 256, 0, stream>>>(os, wsp + (size_t)3*3*262144, bn2 + 3*1024, zsp, 1.0f);

  // 5) depthwise conv + BN(4) + residual
  k_dwc<<<dim3(CC, BB, TT), 256, 0, stream>>>(zsp, x, dwc_w, dwc_b,
      bn_g + 4*CC, bn_b + 4*CC, bn_m + 4*CC, bn_v + 4*CC, out);
}

// Round 4
// 408.462 us; speedup vs baseline: 2.5777x; 1.0849x over previous
//
#include <hip/hip_runtime.h>

#define TT 4
#define BB 32
#define CC 512
#define NN 256
#define DH 64

typedef unsigned char u8;
typedef unsigned short ushort_t;
typedef unsigned int uint_t;
typedef unsigned long long u64;

typedef short bf16x8 __attribute__((ext_vector_type(8)));
typedef float f32x4 __attribute__((ext_vector_type(4)));

typedef __attribute__((address_space(1))) const void gv_t;
typedef __attribute__((address_space(3))) void lv_t;

static __device__ __forceinline__ void gload16(const void* g, void* l){
  __builtin_amdgcn_global_load_lds((gv_t*)g, (lv_t*)l, 16, 0, 0);
}

// ---- helpers ----------------------------------------------------------
static __device__ __forceinline__ unsigned int pack4(unsigned int w){
  return (w & 1u) | ((w >> 7) & 2u) | ((w >> 14) & 4u) | ((w >> 21) & 8u);
}
static __device__ __forceinline__ unsigned int f2bf(float f){
  unsigned int u = __float_as_uint(f);
  return (u + 0x7FFFu + ((u >> 16) & 1u)) >> 16;   // RNE
}
static __device__ __forceinline__ float bf2f(unsigned int b){
  return __uint_as_float(b << 16);
}

// ---- K0: prep — weight 3-way bf16 split + folded BN params ------------
__global__ __launch_bounds__(256) void k_prep(
    const float* __restrict__ qw, const float* __restrict__ kw,
    const float* __restrict__ vw, const float* __restrict__ pw,
    const float* __restrict__ bg, const float* __restrict__ bb,
    const float* __restrict__ bm, const float* __restrict__ bv,
    const float* __restrict__ pb,
    ushort_t* __restrict__ wsp, float* __restrict__ bn2)
{
  int bid = blockIdx.x;
  if (bid < 4096){
    int idx = bid*256 + threadIdx.x;      // 4 * 512*512
    int g   = idx >> 18;
    int rem = idx & 262143;
    const float* W = (g==0)? qw : (g==1)? kw : (g==2)? vw : pw;
    float wv = W[rem];
    unsigned int u1 = f2bf(wv);  float r1 = wv - bf2f(u1);
    unsigned int u2 = f2bf(r1);  float r2 = r1 - bf2f(u2);
    unsigned int u3 = f2bf(r2);
    size_t base = (size_t)g*3*262144 + rem;
    wsp[base            ] = (ushort_t)u1;
    wsp[base + 262144   ] = (ushort_t)u2;
    wsp[base + 2*262144 ] = (ushort_t)u3;
  } else {
    for (int i = threadIdx.x; i < 2048; i += 256){
      int g = i >> 9, d = i & 511;
      float inv = bg[g*512+d] / sqrtf(bv[g*512+d] + 1e-5f);
      float bt  = bb[g*512+d] - bm[g*512+d]*inv + ((g==3)? pb[d]*inv : 0.f);
      bn2[i*2+0] = inv;
      bn2[i*2+1] = bt;
    }
  }
}

// ---- K1: LIF on x -> binary spikes ------------------------------------
__global__ __launch_bounds__(256) void k_lif_x(const float* __restrict__ x,
                                               u8* __restrict__ xs){
  const int PL = BB*CC*NN;
  int i = blockIdx.x*256 + threadIdx.x;
  float v = 0.f;
#pragma unroll
  for (int t=0;t<TT;++t){
    float xv = x[(size_t)t*PL + i];
    v = v + (xv - v)*0.5f;
    if (v >= 1.0f){ xs[(size_t)t*PL + i] = 1; v = 0.f; }
    else          { xs[(size_t)t*PL + i] = 0; }
  }
}

// ---- K2: MFMA GEMM (3-split bf16) + BN + LIF --------------------------
// block: 128d x 64n x 4t for one b.  4 waves, each 32d x 64n x 4t.
// out_qt != null: write ONLY transposed per-head u8 spikes [t][b][h][n][d]
__global__ __launch_bounds__(256, 2) void k_gemm_mfma(
    const u8* __restrict__ act, const ushort_t* __restrict__ wsp,
    const float* __restrict__ bn2, u8* __restrict__ out,
    u8* __restrict__ out_qt, float vth)
{
  __shared__ __align__(16) ushort_t Alds[3][128][32];   // [split][d][k] (chunk-swizzled)
  __shared__ __align__(16) ushort_t Blds[4][4][16][40]; // [t][nf][n%16][k(+pad)]

  const int b  = blockIdx.y;
  const int d0 = (blockIdx.x >> 2) * 128;
  const int n0 = (blockIdx.x & 3) * 64;
  const int tid = threadIdx.x;
  const int l   = tid & 63;
  const int wvi = tid >> 6;

  f32x4 acc[2][4][4];
#pragma unroll
  for (int df=0; df<2; ++df)
#pragma unroll
    for (int nf=0; nf<4; ++nf)
#pragma unroll
      for (int t=0; t<4; ++t)
        acc[df][nf][t] = (f32x4){0.f,0.f,0.f,0.f};

  // B-stage thread mapping
  const int ts = tid >> 6;
  const int kp = (tid >> 2) & 15;
  const int nr = tid & 3;
  const int kq = kp >> 2, jj = kp & 3;

  for (int c0 = 0; c0 < CC; c0 += 32){
    // ---- stage A via global_load_lds (16B), source chunk XOR-swizzled ----
#pragma unroll
    for (int i=0; i<6; ++i){
      int id  = i*256 + tid;              // 0..1535 16B chunks
      int s   = id >> 9;
      int rem = id & 511;
      int d   = rem >> 2, p = rem & 3;
      int g   = p ^ ((d + (d>>2)) & 3);
      const ushort_t* src = wsp + (size_t)s*262144 + (size_t)(d0+d)*512 + c0 + g*8;
      gload16(src, (ushort_t*)Alds + (size_t)id*8);
    }
    // ---- stage B: spikes u8 -> bf16, 2 c-rows x 16 n per thread ----
    {
      const u8* sp = act + (((size_t)ts*BB + b)*CC + (c0 + kp*2))*NN + n0 + nr*16;
      uint4 r0 = *(const uint4*)sp;
      uint4 r1 = *(const uint4*)(sp + NN);
      uint_t wa[4] = {r0.x, r0.y, r0.z, r0.w};
      uint_t wb[4] = {r1.x, r1.y, r1.z, r1.w};
#pragma unroll
      for (int c4=0; c4<4; ++c4){
#pragma unroll
        for (int by=0; by<4; ++by){
          int i = c4*4 + by;
          uint_t b0 = (wa[c4] >> (8*by)) & 1u;
          uint_t b1 = (wb[c4] >> (8*by)) & 1u;
          uint_t hv = b0*0x3F80u + b1*0x3F800000u;  // two bf16 (c, c+1)
          *((uint_t*)&Blds[ts][nr][i][kq*8] + jj) = hv;
        }
      }
    }
    __syncthreads();

    // ---- fragments + MFMA ----
    bf16x8 Af[3][2];
#pragma unroll
    for (int s=0; s<3; ++s)
#pragma unroll
      for (int df=0; df<2; ++df){
        int row = wvi*32 + df*16 + (l&15);
        int pc  = (l>>4) ^ ((row + (row>>2)) & 3);
        Af[s][df] = *(const bf16x8*)&Alds[s][row][pc*8];
      }

#pragma unroll
    for (int nf=0; nf<4; ++nf){
      bf16x8 Bf[4];
#pragma unroll
      for (int t=0; t<4; ++t)
        Bf[t] = *(const bf16x8*)&Blds[t][nf][l&15][(l>>4)*8];
#pragma unroll
      for (int s=0; s<3; ++s)
#pragma unroll
        for (int df=0; df<2; ++df)
#pragma unroll
          for (int t=0; t<4; ++t)
            acc[df][nf][t] = __builtin_amdgcn_mfma_f32_16x16x32_bf16(
                Af[s][df], Bf[t], acc[df][nf][t], 0, 0, 0);
    }
    __syncthreads();
  }

  // ---- epilogue: BN -> LIF(T) -> u8 spikes ----
  if (out_qt){
    // transposed per-head layout [t][b][h][n][d]
#pragma unroll
    for (int df=0; df<2; ++df){
      int dbase = d0 + wvi*32 + df*16 + ((l>>4)<<2);
      int h = dbase >> 6, dh = dbase & 63;
      float inv4[4], bt4[4];
#pragma unroll
      for (int r=0;r<4;++r){ inv4[r] = bn2[(dbase+r)*2]; bt4[r] = bn2[(dbase+r)*2+1]; }
#pragma unroll
      for (int nf=0; nf<4; ++nf){
        int n = n0 + nf*16 + (l&15);
        float vm0=0.f, vm1=0.f, vm2=0.f, vm3=0.f;
#pragma unroll
        for (int t=0; t<4; ++t){
          uchar4 sv;
          float y0 = acc[df][nf][t][0]*inv4[0] + bt4[0];
          vm0 = vm0 + (y0 - vm0)*0.5f; sv.x = (vm0 >= vth); if (sv.x) vm0 = 0.f;
          float y1 = acc[df][nf][t][1]*inv4[1] + bt4[1];
          vm1 = vm1 + (y1 - vm1)*0.5f; sv.y = (vm1 >= vth); if (sv.y) vm1 = 0.f;
          float y2 = acc[df][nf][t][2]*inv4[2] + bt4[2];
          vm2 = vm2 + (y2 - vm2)*0.5f; sv.z = (vm2 >= vth); if (sv.z) vm2 = 0.f;
          float y3 = acc[df][nf][t][3]*inv4[3] + bt4[3];
          vm3 = vm3 + (y3 - vm3)*0.5f; sv.w = (vm3 >= vth); if (sv.w) vm3 = 0.f;
          *(uchar4*)(out_qt + ((((size_t)t*BB + b)*8 + h)*256 + n)*64 + dh) = sv;
        }
      }
    }
  } else {
#pragma unroll
    for (int df=0; df<2; ++df){
#pragma unroll
      for (int r=0; r<4; ++r){
        int d = d0 + wvi*32 + df*16 + ((l>>4)<<2) + r;
        float inv = bn2[d*2+0], bt = bn2[d*2+1];
#pragma unroll
        for (int nf=0; nf<4; ++nf){
          int n = n0 + nf*16 + (l&15);
          float v = 0.f;
#pragma unroll
          for (int t=0; t<4; ++t){
            float y = acc[df][nf][t][r] * inv + bt;
            v = v + (y - v)*0.5f;
            u8 s = (v >= vth);
            out[(((size_t)t*BB + b)*CC + d)*NN + n] = s;
            if (s) v = 0.f;
          }
        }
      }
    }
  }
}

// ---- K3: attention per (b,h): kv popcount (exact), o = q@kv via MFMA,
//          LIF(0.5) over T with in-register membranes ------------------
__global__ __launch_bounds__(256, 1) void k_attn(const u8* __restrict__ qt,
                                                 const u8* __restrict__ ks,
                                                 const u8* __restrict__ vs,
                                                 u8* __restrict__ os)
{
  const int h = blockIdx.x, b = blockIdx.y;
  __shared__ u64 Kb[64][5];                    // padded rows (40B)
  __shared__ u64 Vb[64][5];
  __shared__ __align__(16) ushort_t kvbf[64][88];  // [e][d] bf16, padded
  const int tid = threadIdx.x;
  const int l   = tid & 63;
  const int wvi = tid >> 6;

  f32x4 vm[4][4];
#pragma unroll
  for (int nf=0;nf<4;++nf)
#pragma unroll
    for (int ef=0;ef<4;++ef) vm[nf][ef] = (f32x4){0.f,0.f,0.f,0.f};

  for (int t=0;t<TT;++t){
    size_t base  = ((size_t)t*BB + b)*CC*NN + (size_t)h*DH*NN;
    const u8* qtb = qt + (((size_t)t*BB + b)*8 + h)*256*64;

    // ---- A-frags (q^T) from global, issued early to hide latency ----
    bf16x8 aq[4][2];
#pragma unroll
    for (int nf=0; nf<4; ++nf){
      int n = wvi*64 + nf*16 + (l&15);
#pragma unroll
      for (int kf=0; kf<2; ++kf){
        uint2 qu = *(const uint2*)(qtb + (size_t)n*64 + kf*32 + (l>>4)*8);
        union { uint_t u[4]; bf16x8 v; } cv;
        cv.u[0] = (qu.x & 1u)*0x3F80u + ((qu.x >> 8) & 1u)*0x3F800000u;
        cv.u[1] = ((qu.x >> 16) & 1u)*0x3F80u + ((qu.x >> 24) & 1u)*0x3F800000u;
        cv.u[2] = (qu.y & 1u)*0x3F80u + ((qu.y >> 8) & 1u)*0x3F800000u;
        cv.u[3] = ((qu.y >> 16) & 1u)*0x3F80u + ((qu.y >> 24) & 1u)*0x3F800000u;
        aq[nf][kf] = cv.v;
      }
    }

    // ---- bitpack K,V: Kb[d] = 256 bits over n ----
#pragma unroll
    for (int p=0;p<4;++p){
      int idx = p*256 + tid;
      int d = idx >> 4;
      int piece = idx & 15;
      uint4 ku = *(const uint4*)(ks + base + (size_t)d*NN + piece*16);
      uint4 vu = *(const uint4*)(vs + base + (size_t)d*NN + piece*16);
      unsigned int kp16 = pack4(ku.x) | (pack4(ku.y)<<4) | (pack4(ku.z)<<8) | (pack4(ku.w)<<12);
      unsigned int vp16 = pack4(vu.x) | (pack4(vu.y)<<4) | (pack4(vu.z)<<8) | (pack4(vu.w)<<12);
      ((ushort_t*)Kb)[d*20 + piece] = (ushort_t)kp16;
      ((ushort_t*)Vb)[d*20 + piece] = (ushort_t)vp16;
    }
    __syncthreads();

    // ---- kv[d][e] popcount -> kvbf[e][d] (bf16, exact ints <=256) ----
    {
      int dd0 = (tid >> 4)*4, ee0 = (tid & 15)*4;
      int cnt[4][4] = {};
#pragma unroll
      for (int wi=0; wi<4; ++wi){
        u64 kw[4], vw[4];
#pragma unroll
        for (int i=0;i<4;++i) kw[i] = Kb[dd0+i][wi];
#pragma unroll
        for (int j=0;j<4;++j) vw[j] = Vb[ee0+j][wi];
#pragma unroll
        for (int i=0;i<4;++i)
#pragma unroll
          for (int j=0;j<4;++j)
            cnt[i][j] += __popcll(kw[i] & vw[j]);
      }
#pragma unroll
      for (int i=0;i<4;++i)
#pragma unroll
        for (int j=0;j<4;++j)
          kvbf[ee0+j][dd0+i] = (ushort_t)(__float_as_uint((float)cnt[i][j]) >> 16);
    }
    __syncthreads();

    // ---- o = q @ kv via MFMA; scale, LIF, store ----
    f32x4 acc[4][4];
#pragma unroll
    for (int nf=0;nf<4;++nf)
#pragma unroll
      for (int ef=0;ef<4;++ef) acc[nf][ef] = (f32x4){0.f,0.f,0.f,0.f};

#pragma unroll
    for (int ef=0; ef<4; ++ef){
      bf16x8 bv[2];
#pragma unroll
      for (int kf=0; kf<2; ++kf)
        bv[kf] = *(const bf16x8*)&kvbf[ef*16 + (l&15)][kf*32 + (l>>4)*8];
#pragma unroll
      for (int nf=0; nf<4; ++nf)
#pragma unroll
        for (int kf=0; kf<2; ++kf)
          acc[nf][ef] = __builtin_amdgcn_mfma_f32_16x16x32_bf16(
              aq[nf][kf], bv[kf], acc[nf][ef], 0, 0, 0);
    }

#pragma unroll
    for (int nf=0; nf<4; ++nf){
#pragma unroll
      for (int ef=0; ef<4; ++ef){
        int e = ef*16 + (l&15);
        int n4 = wvi*64 + nf*16 + ((l>>4)<<2);
        uchar4 sv;
        float o0 = acc[nf][ef][0]*0.125f;
        vm[nf][ef][0] += (o0 - vm[nf][ef][0])*0.5f; sv.x = (vm[nf][ef][0] >= 0.5f); if (sv.x) vm[nf][ef][0] = 0.f;
        float o1 = acc[nf][ef][1]*0.125f;
        vm[nf][ef][1] += (o1 - vm[nf][ef][1])*0.5f; sv.y = (vm[nf][ef][1] >= 0.5f); if (sv.y) vm[nf][ef][1] = 0.f;
        float o2 = acc[nf][ef][2]*0.125f;
        vm[nf][ef][2] += (o2 - vm[nf][ef][2])*0.5f; sv.z = (vm[nf][ef][2] >= 0.5f); if (sv.z) vm[nf][ef][2] = 0.f;
        float o3 = acc[nf][ef][3]*0.125f;
        vm[nf][ef][3] += (o3 - vm[nf][ef][3])*0.5f; sv.w = (vm[nf][ef][3] >= 0.5f); if (sv.w) vm[nf][ef][3] = 0.f;
        *(uchar4*)(os + base + (size_t)e*NN + n4) = sv;
      }
    }
    __syncthreads();   // protect Kb/Vb/kvbf for next t (stores done by all waves)
  }
}

// ---- K5: depthwise 5x5 + bias -> BN -> + identity ---------------------
__global__ __launch_bounds__(256) void k_dwc(const u8* __restrict__ zs,
                                             const float* __restrict__ x,
                                             const float* __restrict__ dwc_w,
                                             const float* __restrict__ dwc_b,
                                             const float* __restrict__ g4,
                                             const float* __restrict__ b4,
                                             const float* __restrict__ m4,
                                             const float* __restrict__ v4,
                                             float* __restrict__ out)
{
  const int c = blockIdx.x, b = blockIdx.y, t = blockIdx.z;
  __shared__ float zp[20][20];
  __shared__ float wk[25];
  const int tid = threadIdx.x;
  size_t base = (((size_t)t*BB + b)*CC + c)*NN;

  for (int idx = tid; idx < 400; idx += 256){
    int yy = idx/20 - 2, xx = idx%20 - 2;
    float v = 0.f;
    if (yy >= 0 && yy < 16 && xx >= 0 && xx < 16) v = (float)zs[base + yy*16 + xx];
    zp[idx/20][idx%20] = v;
  }
  if (tid < 25) wk[tid] = dwc_w[c*25 + tid];
  __syncthreads();

  const int py = tid >> 4, px = tid & 15;
  float s = 0.f;
#pragma unroll
  for (int i=0;i<5;++i)
#pragma unroll
    for (int j=0;j<5;++j)
      s = fmaf(zp[py+i][px+j], wk[i*5+j], s);
  s += dwc_b[c];
  float inv = g4[c] / sqrtf(v4[c] + 1e-5f);
  float r = (s - m4[c])*inv + b4[c] + x[base + tid];
  out[base + tid] = r;
}

// ---- launch -----------------------------------------------------------
extern "C" void kernel_launch(void* const* d_in, const int* in_sizes, int n_in,
                              void* d_out, int out_size, void* d_ws, size_t ws_size,
                              hipStream_t stream) {
  const float* x      = (const float*)d_in[0];
  const float* q_w    = (const float*)d_in[1];
  const float* k_w    = (const float*)d_in[2];
  const float* v_w    = (const float*)d_in[3];
  const float* proj_w = (const float*)d_in[4];
  const float* proj_b = (const float*)d_in[5];
  const float* dwc_w  = (const float*)d_in[6];
  const float* dwc_b  = (const float*)d_in[7];
  const float* bn_g   = (const float*)d_in[8];
  const float* bn_b   = (const float*)d_in[9];
  const float* bn_m   = (const float*)d_in[10];
  const float* bn_v   = (const float*)d_in[11];
  float* out = (float*)d_out;

  const size_t SZ = (size_t)TT*BB*CC*NN;   // 16,777,216
  u8* xs  = (u8*)d_ws;
  u8* qtp = xs + SZ;     // q spikes, transposed per-head [t][b][h][n][d]
  u8* ks  = qtp + SZ;
  u8* vs  = ks + SZ;
  u8* os  = vs + SZ;
  u8* zsp = os + SZ;
  ushort_t* wsp = (ushort_t*)(zsp + SZ);          // 4*3*512*512 bf16 = 6.29MB
  float* bn2    = (float*)(wsp + (size_t)4*3*262144);  // 4*512*2 f32

  // 0) prep: weight splits + BN folds
  k_prep<<<4097, 256, 0, stream>>>(q_w, k_w, v_w, proj_w,
      bn_g, bn_b, bn_m, bn_v, proj_b, wsp, bn2);

  // 1) input LIF
  k_lif_x<<<(BB*CC*NN)/256, 256, 0, stream>>>(x, xs);

  // 2) q,k,v: MFMA matmul + BN(0/1/2) + LIF(1.0)
  dim3 gg(16, BB);
  k_gemm_mfma<<<gg, 256, 0, stream>>>(xs, wsp + (size_t)0*3*262144, bn2 + 0*1024, nullptr, qtp, 1.0f);
  k_gemm_mfma<<<gg, 256, 0, stream>>>(xs, wsp + (size_t)1*3*262144, bn2 + 1*1024, ks, nullptr, 1.0f);
  k_gemm_mfma<<<gg, 256, 0, stream>>>(xs, wsp + (size_t)2*3*262144, bn2 + 2*1024, vs, nullptr, 1.0f);

  // 3) attention (exact) + LIF(0.5)
  k_attn<<<dim3(8, BB), 256, 0, stream>>>(qtp, ks, vs, os);

  // 4) proj: MFMA matmul + bias + BN(3) + LIF(1.0)
  k_gemm_mfma<<<gg, 256, 0, stream>>>(os, wsp + (size_t)3*3*262144, bn2 + 3*1024, zsp, nullptr, 1.0f);

  // 5) depthwise conv + BN(4) + residual
  k_dwc<<<dim3(CC, BB, TT), 256, 0, stream>>>(zsp, x, dwc_w, dwc_b,
      bn_g + 4*CC, bn_b + 4*CC, bn_m + 4*CC, bn_v + 4*CC, out);
}

// Round 5
// 356.482 us; speedup vs baseline: 2.9536x; 1.1458x over previous
//
#include <hip/hip_runtime.h>
#include <hip/hip_fp16.h>

#define TT 4
#define BB 32
#define CC 512
#define NN 256
#define DH 64

typedef unsigned char u8;
typedef unsigned short ushort_t;
typedef unsigned int uint_t;
typedef unsigned long long u64;

typedef _Float16 f16;
typedef _Float16 f16x8 __attribute__((ext_vector_type(8)));
typedef float f32x4 __attribute__((ext_vector_type(4)));

typedef __attribute__((address_space(1))) const void gv_t;
typedef __attribute__((address_space(3))) void lv_t;

static __device__ __forceinline__ void gload16(const void* g, void* l){
  __builtin_amdgcn_global_load_lds((gv_t*)g, (lv_t*)l, 16, 0, 0);
}

// ---- helpers ----------------------------------------------------------
static __device__ __forceinline__ unsigned int pack4(unsigned int w){
  return (w & 1u) | ((w >> 7) & 2u) | ((w >> 14) & 4u) | ((w >> 21) & 8u);
}

// ---- K0: prep — weight 2-way f16 split + folded BN params -------------
// w = h1 + h2*2^-11 exactly to ~4 fp32 ulps:
//   h1 = f16(w); h2 = f16((w-h1)*2048)   (all operands normal-range f16)
__global__ __launch_bounds__(256) void k_prep(
    const float* __restrict__ qw, const float* __restrict__ kw,
    const float* __restrict__ vw, const float* __restrict__ pw,
    const float* __restrict__ bg, const float* __restrict__ bb,
    const float* __restrict__ bm, const float* __restrict__ bv,
    const float* __restrict__ pb, const float* __restrict__ dwcb,
    ushort_t* __restrict__ wsp, float* __restrict__ bn2)
{
  int bid = blockIdx.x;
  if (bid < 4096){
    int idx = bid*256 + threadIdx.x;      // 4 * 512*512
    int g   = idx >> 18;
    int rem = idx & 262143;
    const float* W = (g==0)? qw : (g==1)? kw : (g==2)? vw : pw;
    float wv = W[rem];
    __half h1 = __float2half(wv);
    float h1f = __half2float(h1);
    __half h2 = __float2half((wv - h1f) * 2048.0f);
    size_t base = (size_t)g*2*262144 + rem;
    wsp[base         ] = __half_as_ushort(h1);
    wsp[base + 262144] = __half_as_ushort(h2);
  } else {
    for (int i = threadIdx.x; i < 2560; i += 256){   // 5 BN groups
      int g = i >> 9, d = i & 511;
      float inv = bg[i] / sqrtf(bv[i] + 1e-5f);
      float extra = (g==3)? pb[d] : (g==4)? dwcb[d] : 0.f;
      float bt  = bb[i] - bm[i]*inv + extra*inv;
      bn2[i*2+0] = inv;
      bn2[i*2+1] = bt;
    }
  }
}

// ---- K1: LIF on x -> binary spikes (float4 vectorized) ----------------
__global__ __launch_bounds__(256) void k_lif_x(const float* __restrict__ x,
                                               u8* __restrict__ xs){
  const int PL = BB*CC*NN;
  int i = (blockIdx.x*256 + threadIdx.x)*4;
  float4 v = make_float4(0.f,0.f,0.f,0.f);
#pragma unroll
  for (int t=0;t<TT;++t){
    float4 xv = *(const float4*)(x + (size_t)t*PL + i);
    uchar4 s;
    v.x = v.x + (xv.x - v.x)*0.5f; s.x = (v.x >= 1.0f); if (s.x) v.x = 0.f;
    v.y = v.y + (xv.y - v.y)*0.5f; s.y = (v.y >= 1.0f); if (s.y) v.y = 0.f;
    v.z = v.z + (xv.z - v.z)*0.5f; s.z = (v.z >= 1.0f); if (s.z) v.z = 0.f;
    v.w = v.w + (xv.w - v.w)*0.5f; s.w = (v.w >= 1.0f); if (s.w) v.w = 0.f;
    *(uchar4*)(xs + (size_t)t*PL + i) = s;
  }
}

// ---- K2: MFMA GEMM (2-pass f16 split) + BN + LIF ----------------------
// block: 128d x 64n x 4t for one b.  4 waves, each 32d x 64n x 4t.
// pass2 multiplies the B (spike) frags by exact f16 2^-11 in-register.
__global__ __launch_bounds__(256, 2) void k_gemm_mfma(
    const u8* __restrict__ act, const ushort_t* __restrict__ wsp,
    const float* __restrict__ bn2, u8* __restrict__ out,
    u8* __restrict__ out_qt, float vth)
{
  __shared__ __align__(16) ushort_t Alds[2][128][32];   // [split][d][k] (chunk-swizzled)
  __shared__ __align__(16) ushort_t Blds[4][4][16][40]; // [t][nf][n%16][k(+pad)]

  const int b  = blockIdx.y;
  const int d0 = (blockIdx.x >> 2) * 128;
  const int n0 = (blockIdx.x & 3) * 64;
  const int tid = threadIdx.x;
  const int l   = tid & 63;
  const int wvi = tid >> 6;

  f32x4 acc[2][4][4];
#pragma unroll
  for (int df=0; df<2; ++df)
#pragma unroll
    for (int nf=0; nf<4; ++nf)
#pragma unroll
      for (int t=0; t<4; ++t)
        acc[df][nf][t] = (f32x4){0.f,0.f,0.f,0.f};

  // B-stage thread mapping
  const int ts = tid >> 6;
  const int kp = (tid >> 2) & 15;
  const int nr = tid & 3;
  const int kq = kp >> 2, jj = kp & 3;

  const f16 sc = (f16)4.8828125e-4f;   // 2^-11, exact

  for (int c0 = 0; c0 < CC; c0 += 32){
    // ---- stage A via global_load_lds (16B), source chunk XOR-swizzled ----
#pragma unroll
    for (int i=0; i<4; ++i){
      int id  = i*256 + tid;              // 0..1023 16B chunks
      int s   = id >> 9;
      int rem = id & 511;
      int d   = rem >> 2, p = rem & 3;
      int g   = p ^ ((d + (d>>2)) & 3);
      const ushort_t* src = wsp + (size_t)s*262144 + (size_t)(d0+d)*512 + c0 + g*8;
      gload16(src, (ushort_t*)Alds + (size_t)id*8);
    }
    // ---- stage B: spikes u8 -> f16, 2 c-rows x 16 n per thread ----
    {
      const u8* sp = act + (((size_t)ts*BB + b)*CC + (c0 + kp*2))*NN + n0 + nr*16;
      uint4 r0 = *(const uint4*)sp;
      uint4 r1 = *(const uint4*)(sp + NN);
      uint_t wa[4] = {r0.x, r0.y, r0.z, r0.w};
      uint_t wb[4] = {r1.x, r1.y, r1.z, r1.w};
#pragma unroll
      for (int c4=0; c4<4; ++c4){
#pragma unroll
        for (int by=0; by<4; ++by){
          int i = c4*4 + by;
          uint_t b0 = (wa[c4] >> (8*by)) & 1u;
          uint_t b1 = (wb[c4] >> (8*by)) & 1u;
          uint_t hv = b0*0x3C00u + b1*0x3C000000u;  // two f16 (c, c+1)
          *((uint_t*)&Blds[ts][nr][i][kq*8] + jj) = hv;
        }
      }
    }
    __syncthreads();

    // ---- fragments + MFMA ----
    f16x8 Af[2][2];
#pragma unroll
    for (int s=0; s<2; ++s)
#pragma unroll
      for (int df=0; df<2; ++df){
        int row = wvi*32 + df*16 + (l&15);
        int pc  = (l>>4) ^ ((row + (row>>2)) & 3);
        Af[s][df] = *(const f16x8*)&Alds[s][row][pc*8];
      }

#pragma unroll
    for (int nf=0; nf<4; ++nf){
      f16x8 Bf[4];
#pragma unroll
      for (int t=0; t<4; ++t)
        Bf[t] = *(const f16x8*)&Blds[t][nf][l&15][(l>>4)*8];
      // pass 1: h1 * s
#pragma unroll
      for (int df=0; df<2; ++df)
#pragma unroll
        for (int t=0; t<4; ++t)
          acc[df][nf][t] = __builtin_amdgcn_mfma_f32_16x16x32_f16(
              Af[0][df], Bf[t], acc[df][nf][t], 0, 0, 0);
      // pass 2: h2 * (s * 2^-11)   (exact scale on binary spikes)
#pragma unroll
      for (int t=0; t<4; ++t)
        Bf[t] = Bf[t] * sc;
#pragma unroll
      for (int df=0; df<2; ++df)
#pragma unroll
        for (int t=0; t<4; ++t)
          acc[df][nf][t] = __builtin_amdgcn_mfma_f32_16x16x32_f16(
              Af[1][df], Bf[t], acc[df][nf][t], 0, 0, 0);
    }
    __syncthreads();
  }

  // ---- epilogue: BN -> LIF(T) -> u8 spikes ----
  if (out_qt){
    // transposed per-head layout [t][b][h][n][d]
#pragma unroll
    for (int df=0; df<2; ++df){
      int dbase = d0 + wvi*32 + df*16 + ((l>>4)<<2);
      int h = dbase >> 6, dh = dbase & 63;
      float inv4[4], bt4[4];
#pragma unroll
      for (int r=0;r<4;++r){ inv4[r] = bn2[(dbase+r)*2]; bt4[r] = bn2[(dbase+r)*2+1]; }
#pragma unroll
      for (int nf=0; nf<4; ++nf){
        int n = n0 + nf*16 + (l&15);
        float vm0=0.f, vm1=0.f, vm2=0.f, vm3=0.f;
#pragma unroll
        for (int t=0; t<4; ++t){
          uchar4 sv;
          float y0 = acc[df][nf][t][0]*inv4[0] + bt4[0];
          vm0 = vm0 + (y0 - vm0)*0.5f; sv.x = (vm0 >= vth); if (sv.x) vm0 = 0.f;
          float y1 = acc[df][nf][t][1]*inv4[1] + bt4[1];
          vm1 = vm1 + (y1 - vm1)*0.5f; sv.y = (vm1 >= vth); if (sv.y) vm1 = 0.f;
          float y2 = acc[df][nf][t][2]*inv4[2] + bt4[2];
          vm2 = vm2 + (y2 - vm2)*0.5f; sv.z = (vm2 >= vth); if (sv.z) vm2 = 0.f;
          float y3 = acc[df][nf][t][3]*inv4[3] + bt4[3];
          vm3 = vm3 + (y3 - vm3)*0.5f; sv.w = (vm3 >= vth); if (sv.w) vm3 = 0.f;
          *(uchar4*)(out_qt + ((((size_t)t*BB + b)*8 + h)*256 + n)*64 + dh) = sv;
        }
      }
    }
  } else {
#pragma unroll
    for (int df=0; df<2; ++df){
#pragma unroll
      for (int r=0; r<4; ++r){
        int d = d0 + wvi*32 + df*16 + ((l>>4)<<2) + r;
        float inv = bn2[d*2+0], bt = bn2[d*2+1];
#pragma unroll
        for (int nf=0; nf<4; ++nf){
          int n = n0 + nf*16 + (l&15);
          float v = 0.f;
#pragma unroll
          for (int t=0; t<4; ++t){
            float y = acc[df][nf][t][r] * inv + bt;
            v = v + (y - v)*0.5f;
            u8 s = (v >= vth);
            out[(((size_t)t*BB + b)*CC + d)*NN + n] = s;
            if (s) v = 0.f;
          }
        }
      }
    }
  }
}

// ---- K3: attention per (b,h): kv popcount (exact), o = q@kv via MFMA,
//          LIF(0.5) over T with in-register membranes ------------------
__global__ __launch_bounds__(256, 1) void k_attn(const u8* __restrict__ qt,
                                                 const u8* __restrict__ ks,
                                                 const u8* __restrict__ vs,
                                                 u8* __restrict__ os)
{
  const int h = blockIdx.x, b = blockIdx.y;
  __shared__ u64 Kb[64][5];                    // padded rows (40B)
  __shared__ u64 Vb[64][5];
  __shared__ __align__(16) ushort_t kvbf[64][88];  // [e][d] bf16, padded
  const int tid = threadIdx.x;
  const int l   = tid & 63;
  const int wvi = tid >> 6;

  typedef short bf16x8 __attribute__((ext_vector_type(8)));

  f32x4 vm[4][4];
#pragma unroll
  for (int nf=0;nf<4;++nf)
#pragma unroll
    for (int ef=0;ef<4;++ef) vm[nf][ef] = (f32x4){0.f,0.f,0.f,0.f};

  for (int t=0;t<TT;++t){
    size_t base  = ((size_t)t*BB + b)*CC*NN + (size_t)h*DH*NN;
    const u8* qtb = qt + (((size_t)t*BB + b)*8 + h)*256*64;

    // ---- A-frags (q^T) from global, issued early to hide latency ----
    bf16x8 aq[4][2];
#pragma unroll
    for (int nf=0; nf<4; ++nf){
      int n = wvi*64 + nf*16 + (l&15);
#pragma unroll
      for (int kf=0; kf<2; ++kf){
        uint2 qu = *(const uint2*)(qtb + (size_t)n*64 + kf*32 + (l>>4)*8);
        union { uint_t u[4]; bf16x8 v; } cv;
        cv.u[0] = (qu.x & 1u)*0x3F80u + ((qu.x >> 8) & 1u)*0x3F800000u;
        cv.u[1] = ((qu.x >> 16) & 1u)*0x3F80u + ((qu.x >> 24) & 1u)*0x3F800000u;
        cv.u[2] = (qu.y & 1u)*0x3F80u + ((qu.y >> 8) & 1u)*0x3F800000u;
        cv.u[3] = ((qu.y >> 16) & 1u)*0x3F80u + ((qu.y >> 24) & 1u)*0x3F800000u;
        aq[nf][kf] = cv.v;
      }
    }

    // ---- bitpack K,V: Kb[d] = 256 bits over n ----
#pragma unroll
    for (int p=0;p<4;++p){
      int idx = p*256 + tid;
      int d = idx >> 4;
      int piece = idx & 15;
      uint4 ku = *(const uint4*)(ks + base + (size_t)d*NN + piece*16);
      uint4 vu = *(const uint4*)(vs + base + (size_t)d*NN + piece*16);
      unsigned int kp16 = pack4(ku.x) | (pack4(ku.y)<<4) | (pack4(ku.z)<<8) | (pack4(ku.w)<<12);
      unsigned int vp16 = pack4(vu.x) | (pack4(vu.y)<<4) | (pack4(vu.z)<<8) | (pack4(vu.w)<<12);
      ((ushort_t*)Kb)[d*20 + piece] = (ushort_t)kp16;
      ((ushort_t*)Vb)[d*20 + piece] = (ushort_t)vp16;
    }
    __syncthreads();

    // ---- kv[d][e] popcount -> kvbf[e][d] (bf16, exact ints <=256) ----
    {
      int dd0 = (tid >> 4)*4, ee0 = (tid & 15)*4;
      int cnt[4][4] = {};
#pragma unroll
      for (int wi=0; wi<4; ++wi){
        u64 kw[4], vw[4];
#pragma unroll
        for (int i=0;i<4;++i) kw[i] = Kb[dd0+i][wi];
#pragma unroll
        for (int j=0;j<4;++j) vw[j] = Vb[ee0+j][wi];
#pragma unroll
        for (int i=0;i<4;++i)
#pragma unroll
          for (int j=0;j<4;++j)
            cnt[i][j] += __popcll(kw[i] & vw[j]);
      }
#pragma unroll
      for (int i=0;i<4;++i)
#pragma unroll
        for (int j=0;j<4;++j)
          kvbf[ee0+j][dd0+i] = (ushort_t)(__float_as_uint((float)cnt[i][j]) >> 16);
    }
    __syncthreads();

    // ---- o = q @ kv via MFMA; scale, LIF, store ----
    f32x4 acc[4][4];
#pragma unroll
    for (int nf=0;nf<4;++nf)
#pragma unroll
      for (int ef=0;ef<4;++ef) acc[nf][ef] = (f32x4){0.f,0.f,0.f,0.f};

#pragma unroll
    for (int ef=0; ef<4; ++ef){
      bf16x8 bv[2];
#pragma unroll
      for (int kf=0; kf<2; ++kf)
        bv[kf] = *(const bf16x8*)&kvbf[ef*16 + (l&15)][kf*32 + (l>>4)*8];
#pragma unroll
      for (int nf=0; nf<4; ++nf)
#pragma unroll
        for (int kf=0; kf<2; ++kf)
          acc[nf][ef] = __builtin_amdgcn_mfma_f32_16x16x32_bf16(
              aq[nf][kf], bv[kf], acc[nf][ef], 0, 0, 0);
    }

#pragma unroll
    for (int nf=0; nf<4; ++nf){
#pragma unroll
      for (int ef=0; ef<4; ++ef){
        int e = ef*16 + (l&15);
        int n4 = wvi*64 + nf*16 + ((l>>4)<<2);
        uchar4 sv;
        float o0 = acc[nf][ef][0]*0.125f;
        vm[nf][ef][0] += (o0 - vm[nf][ef][0])*0.5f; sv.x = (vm[nf][ef][0] >= 0.5f); if (sv.x) vm[nf][ef][0] = 0.f;
        float o1 = acc[nf][ef][1]*0.125f;
        vm[nf][ef][1] += (o1 - vm[nf][ef][1])*0.5f; sv.y = (vm[nf][ef][1] >= 0.5f); if (sv.y) vm[nf][ef][1] = 0.f;
        float o2 = acc[nf][ef][2]*0.125f;
        vm[nf][ef][2] += (o2 - vm[nf][ef][2])*0.5f; sv.z = (vm[nf][ef][2] >= 0.5f); if (sv.z) vm[nf][ef][2] = 0.f;
        float o3 = acc[nf][ef][3]*0.125f;
        vm[nf][ef][3] += (o3 - vm[nf][ef][3])*0.5f; sv.w = (vm[nf][ef][3] >= 0.5f); if (sv.w) vm[nf][ef][3] = 0.f;
        *(uchar4*)(os + base + (size_t)e*NN + n4) = sv;
      }
    }
    __syncthreads();   // protect Kb/Vb/kvbf for next t
  }
}

// ---- K5: depthwise 5x5 + bias -> BN -> + identity (register rows) -----
// one thread per output row (16 px): W=16 -> each input row is one uint4.
__global__ __launch_bounds__(256) void k_dwc(const u8* __restrict__ zs,
                                             const float* __restrict__ x,
                                             const float* __restrict__ dwc_w,
                                             const float* __restrict__ bn2,
                                             float* __restrict__ out)
{
  int idx   = blockIdx.x*256 + threadIdx.x;   // TT*BB*CC*16 = 1,048,576
  int y     = idx & 15;
  int plane = idx >> 4;                       // (t*BB+b)*CC + c
  int c     = plane & (CC-1);
  size_t base = (size_t)plane * NN;

  // 5 input rows (zero outside SAME padding)
  uint4 rows[5];
#pragma unroll
  for (int i=0;i<5;++i){
    int yy = y + i - 2;
    rows[i] = (yy >= 0 && yy < 16) ? *(const uint4*)(zs + base + yy*16)
                                   : make_uint4(0,0,0,0);
  }
  // residual input
  float4 xr[4];
#pragma unroll
  for (int q=0;q<4;++q) xr[q] = *(const float4*)(x + base + y*16 + q*4);

  // per-channel weights + folded BN
  float wk[25];
  const float* wp = dwc_w + c*25;
#pragma unroll
  for (int i=0;i<25;++i) wk[i] = wp[i];
  float inv = bn2[(2048+c)*2+0], bt = bn2[(2048+c)*2+1];

  float acc[16];
#pragma unroll
  for (int i=0;i<16;++i) acc[i] = 0.f;

#pragma unroll
  for (int i=0;i<5;++i){
    float rb[20];
    rb[0]=0.f; rb[1]=0.f; rb[18]=0.f; rb[19]=0.f;
    uint_t wd[4] = {rows[i].x, rows[i].y, rows[i].z, rows[i].w};
#pragma unroll
    for (int q=0;q<4;++q)
#pragma unroll
      for (int k=0;k<4;++k)
        rb[2 + q*4 + k] = (float)((wd[q] >> (8*k)) & 0xffu);
#pragma unroll
    for (int j=0;j<5;++j){
      float wv = wk[i*5+j];
#pragma unroll
      for (int xp=0;xp<16;++xp)
        acc[xp] = fmaf(wv, rb[xp+j], acc[xp]);
    }
  }

#pragma unroll
  for (int q=0;q<4;++q){
    float4 ov;
    ov.x = acc[q*4+0]*inv + bt + xr[q].x;
    ov.y = acc[q*4+1]*inv + bt + xr[q].y;
    ov.z = acc[q*4+2]*inv + bt + xr[q].z;
    ov.w = acc[q*4+3]*inv + bt + xr[q].w;
    *(float4*)(out + base + y*16 + q*4) = ov;
  }
}

// ---- launch -----------------------------------------------------------
extern "C" void kernel_launch(void* const* d_in, const int* in_sizes, int n_in,
                              void* d_out, int out_size, void* d_ws, size_t ws_size,
                              hipStream_t stream) {
  const float* x      = (const float*)d_in[0];
  const float* q_w    = (const float*)d_in[1];
  const float* k_w    = (const float*)d_in[2];
  const float* v_w    = (const float*)d_in[3];
  const float* proj_w = (const float*)d_in[4];
  const float* proj_b = (const float*)d_in[5];
  const float* dwc_w  = (const float*)d_in[6];
  const float* dwc_b  = (const float*)d_in[7];
  const float* bn_g   = (const float*)d_in[8];
  const float* bn_b   = (const float*)d_in[9];
  const float* bn_m   = (const float*)d_in[10];
  const float* bn_v   = (const float*)d_in[11];
  float* out = (float*)d_out;

  const size_t SZ = (size_t)TT*BB*CC*NN;   // 16,777,216
  u8* xs  = (u8*)d_ws;
  u8* qtp = xs + SZ;     // q spikes, transposed per-head [t][b][h][n][d]
  u8* ks  = qtp + SZ;
  u8* vs  = ks + SZ;
  u8* os  = vs + SZ;
  u8* zsp = os + SZ;
  ushort_t* wsp = (ushort_t*)(zsp + SZ);          // 4*2*512*512 f16 = 4.2MB
  float* bn2    = (float*)(wsp + (size_t)4*2*262144);  // 5*512*2 f32

  // 0) prep: weight splits + BN folds
  k_prep<<<4097, 256, 0, stream>>>(q_w, k_w, v_w, proj_w,
      bn_g, bn_b, bn_m, bn_v, proj_b, dwc_b, wsp, bn2);

  // 1) input LIF (float4)
  k_lif_x<<<(BB*CC*NN)/1024, 256, 0, stream>>>(x, xs);

  // 2) q,k,v: MFMA matmul + BN(0/1/2) + LIF(1.0)
  dim3 gg(16, BB);
  k_gemm_mfma<<<gg, 256, 0, stream>>>(xs, wsp + (size_t)0*2*262144, bn2 + 0*1024, nullptr, qtp, 1.0f);
  k_gemm_mfma<<<gg, 256, 0, stream>>>(xs, wsp + (size_t)1*2*262144, bn2 + 1*1024, ks, nullptr, 1.0f);
  k_gemm_mfma<<<gg, 256, 0, stream>>>(xs, wsp + (size_t)2*2*262144, bn2 + 2*1024, vs, nullptr, 1.0f);

  // 3) attention (exact) + LIF(0.5)
  k_attn<<<dim3(8, BB), 256, 0, stream>>>(qtp, ks, vs, os);

  // 4) proj: MFMA matmul + bias + BN(3) + LIF(1.0)
  k_gemm_mfma<<<gg, 256, 0, stream>>>(os, wsp + (size_t)3*2*262144, bn2 + 3*1024, zsp, nullptr, 1.0f);

  // 5) depthwise conv + BN(4) + residual (register-row scheme)
  k_dwc<<<(TT*BB*CC*16)/256, 256, 0, stream>>>(zsp, x, dwc_w, bn2, out);
}